// Round 9
// baseline (599.028 us; speedup 1.0000x reference)
//
#include <hip/hip_runtime.h>
#include <hip/hip_bf16.h>
#include <cstdint>
#include <cstddef>

// ---------------- problem constants ----------------
#define B_    8
#define Q_    2048
#define DIM_  256
#define NH    8
#define HD    32
#define NL    4
#define NP    4
#define DFF   1024
#define LEN_IN_ 13294
#define MV    (B_*LEN_IN_)     // 106352
#define MVPAD 106368           // 831*128
#define MQ    (B_*Q_)          // 16384

typedef unsigned short u16;
typedef unsigned int   u32;
typedef __attribute__((ext_vector_type(8))) short short8;
typedef __attribute__((ext_vector_type(4))) float f32x4v;
typedef __attribute__((ext_vector_type(4))) unsigned short u16x4;

static __device__ __forceinline__ u16 f2bf(float f){
  union { float f; unsigned u; } x; x.f = f;
  unsigned r = x.u + 0x7fffu + ((x.u >> 16) & 1u);
  return (u16)(r >> 16);
}

#define GLDS(gp, lp) __builtin_amdgcn_global_load_lds( \
    (const __attribute__((address_space(1))) void*)(gp), \
    (__attribute__((address_space(3))) void*)(lp), 16, 0, 0)

// ---------------- bf16 MFMA GEMM: barrier-free K-loop ----------------
// 8 waves (512 thr) per 128x128 tile; wave-tile 64x32 -> acc[4][2] (32 AGPR).
// B[N][K] staged to LDS once per 256-K chunk (XOR-swizzled, GLDS); K=256 -> 2
// barriers/block total. A-fragments loaded direct global->reg per wave with
// 1-slot prefetch (slot = 32 K-elems); no per-K-step barrier, waves drift.
// AF32: A fp32, converted in-reg after arrival. A-rows clamped (only padded
// rows OOB; their acc is never stored).
// EPI: 0 f32+bias; 1 bf16+bias; 2 f32+bias+residual; 3 bf16+bias+relu
template<int EPI, bool AF32>
__global__ __launch_bounds__(512, 4)
void gemm_k(const void* __restrict__ Ap, const u16* __restrict__ Bt,
            const float* __restrict__ bias, const float* __restrict__ res,
            void* __restrict__ outp, int N, int K, int Mstore)
{
  __shared__ u16 Bs[128 * 256];             // 64 KB: one 256-wide K chunk of B
  const int t = threadIdx.x;
  const int l = t & 63, wid = t >> 6;       // 8 waves
  const int wm = wid >> 2, wn = wid & 3;    // 2 x 4 wave grid
  const int lr = l & 15, hi = l >> 4;
  const int m0 = blockIdx.x * 128, n0 = blockIdx.y * 128;

  f32x4v acc[4][2];
#pragma unroll
  for (int i = 0; i < 4; ++i)
#pragma unroll
    for (int j = 0; j < 2; ++j) acc[i][j] = 0.f;

  // per-mi A fragment base pointers (row clamped; includes hi*8 col offset)
  const u16*   pA16[4];
  const float* pA32[4];
#pragma unroll
  for (int mi = 0; mi < 4; ++mi) {
    int r = m0 + wm * 64 + mi * 16 + lr;
    r = (r < Mstore) ? r : (Mstore - 1);
    if (AF32) pA32[mi] = (const float*)Ap + (size_t)r * K + hi * 8;
    else      pA16[mi] = (const u16*)Ap + (size_t)r * K + hi * 8;
  }

  const int nchunk = K >> 8;                // 256-wide K chunks
  const int S = K >> 5;                     // total 32-K slots

  short8 af[4];                             // current slot bf16 fragments
  short8 afn[4];                            // next slot (bf16 path)
  float4 pan[8];                            // next slot (fp32 path)

  // prologue: issue slot 0 A loads
  if (AF32) {
#pragma unroll
    for (int mi = 0; mi < 4; ++mi) {
      pan[2*mi]   = *reinterpret_cast<const float4*>(pA32[mi]);
      pan[2*mi+1] = *reinterpret_cast<const float4*>(pA32[mi] + 4);
    }
  } else {
#pragma unroll
    for (int mi = 0; mi < 4; ++mi)
      afn[mi] = *reinterpret_cast<const short8*>(pA16[mi]);
  }

  for (int ck = 0; ck < nchunk; ++ck) {
    if (ck) __syncthreads();                // prior chunk's reads complete
    // ---- stage B chunk into LDS (inverse-swizzled source, linear dest)
#pragma unroll
    for (int i = 0; i < 8; ++i) {
      const int chunk = i * 512 + t;        // 0..4095 16B-chunks
      const int row = chunk >> 5;           // 32 chunks per 256-col row
      const int c16 = chunk & 31;
      const int sc  = c16 ^ (row & 7);
      GLDS(Bt + (size_t)(n0 + row) * K + ck * 256 + sc * 8, Bs + chunk * 8);
    }
    asm volatile("s_waitcnt vmcnt(0)" ::: "memory");
    __syncthreads();                        // B chunk visible to all waves

    // ---- barrier-free inner loop: 8 slots of 32 K-elems
#pragma unroll
    for (int sl = 0; sl < 8; ++sl) {
      const int s = ck * 8 + sl;
      // materialize current slot fragments (kills previous stage regs)
      if (AF32) {
#pragma unroll
        for (int mi = 0; mi < 4; ++mi) {
          short8 pk;
          pk[0]=(short)f2bf(pan[2*mi].x);   pk[1]=(short)f2bf(pan[2*mi].y);
          pk[2]=(short)f2bf(pan[2*mi].z);   pk[3]=(short)f2bf(pan[2*mi].w);
          pk[4]=(short)f2bf(pan[2*mi+1].x); pk[5]=(short)f2bf(pan[2*mi+1].y);
          pk[6]=(short)f2bf(pan[2*mi+1].z); pk[7]=(short)f2bf(pan[2*mi+1].w);
          af[mi] = pk;
        }
      } else {
#pragma unroll
        for (int mi = 0; mi < 4; ++mi) af[mi] = afn[mi];
      }
      // issue next slot's A loads (in flight under the MFMAs)
      if (s + 1 < S) {
        const int ko = (s + 1) * 32;
        if (AF32) {
#pragma unroll
          for (int mi = 0; mi < 4; ++mi) {
            pan[2*mi]   = *reinterpret_cast<const float4*>(pA32[mi] + ko);
            pan[2*mi+1] = *reinterpret_cast<const float4*>(pA32[mi] + ko + 4);
          }
        } else {
#pragma unroll
          for (int mi = 0; mi < 4; ++mi)
            afn[mi] = *reinterpret_cast<const short8*>(pA16[mi] + ko);
        }
      }
      // B fragments from LDS (swizzled; 2-way bank alias only)
      short8 bfr[2];
#pragma unroll
      for (int ni = 0; ni < 2; ++ni) {
        const int r = wn * 32 + ni * 16 + lr;
        const int c = (sl * 4 + hi) ^ (lr & 7);
        bfr[ni] = *reinterpret_cast<const short8*>(Bs + (r * 32 + c) * 8);
      }
#pragma unroll
      for (int mi = 0; mi < 4; ++mi)
#pragma unroll
        for (int ni = 0; ni < 2; ++ni)
          acc[mi][ni] = __builtin_amdgcn_mfma_f32_16x16x32_bf16(af[mi], bfr[ni], acc[mi][ni], 0, 0, 0);
    }
  }

  // ---- epilogue
  const int lr4 = hi;
#pragma unroll
  for (int mi = 0; mi < 4; ++mi) {
    int rowb = m0 + wm * 64 + mi * 16 + lr4 * 4;
#pragma unroll
    for (int ni = 0; ni < 2; ++ni) {
      int col = n0 + wn * 32 + ni * 16 + lr;
      float bb = bias[col];
#pragma unroll
      for (int v = 0; v < 4; ++v) {
        int r = rowb + v;
        if (r < Mstore) {
          float cv = acc[mi][ni][v] + bb;
          if (EPI == 2) cv += res[(size_t)r * N + col];
          if (EPI == 3) cv = fmaxf(cv, 0.f);
          if (EPI == 0 || EPI == 2) ((float*)outp)[(size_t)r * N + col] = cv;
          else                      ((u16*)outp)[(size_t)r * N + col] = f2bf(cv);
        }
      }
    }
  }
}

// ---------------- fused weight prep: all transposes + combined bias ----------------
__global__ void prep_weights(const float* __restrict__ Wv,   const float* __restrict__ Woff,
                             const float* __restrict__ Wattn,const float* __restrict__ Wout,
                             const float* __restrict__ W1,   const float* __restrict__ W2,
                             const float* __restrict__ boff, const float* __restrict__ battn,
                             u16* __restrict__ WvT, u16* __restrict__ WcombT,
                             u16* __restrict__ WoutT, u16* __restrict__ W1T,
                             u16* __restrict__ W2T, float* __restrict__ bcomb)
{
  const int gid = blockIdx.x * 256 + threadIdx.x;
  const int R0 = 65536, R1 = R0 + 98304, R2 = R1 + 65536, R3 = R2 + 262144,
            R4 = R3 + 262144, R5 = R4 + 384;
  if (gid < R0) {
    int n = gid >> 8, k = gid & 255;
    WvT[gid] = f2bf(Wv[(size_t)k * 256 + n]);
  } else if (gid < R1) {
    int lo = gid - R0, n = lo >> 8, k = lo & 255;
    float s = (n < 256) ? Woff[(size_t)k * 256 + n] : Wattn[(size_t)k * 128 + (n - 256)];
    WcombT[lo] = f2bf(s);
  } else if (gid < R2) {
    int lo = gid - R1, n = lo >> 8, k = lo & 255;
    WoutT[lo] = f2bf(Wout[(size_t)k * 256 + n]);
  } else if (gid < R3) {
    int lo = gid - R2, n = lo >> 8, k = lo & 255;
    W1T[lo] = f2bf(W1[(size_t)k * 1024 + n]);
  } else if (gid < R4) {
    int lo = gid - R3, n = lo >> 10, k = lo & 1023;
    W2T[lo] = f2bf(W2[(size_t)k * 256 + n]);
  } else if (gid < R5) {
    int lo = gid - R4;
    bcomb[lo] = (lo < 256) ? boff[lo] : battn[lo - 256];
  }
}

// ---------------- LayerNorm (warp per 256-float row) -> bf16 out ----------------
template<bool ADDPOS>
__global__ __launch_bounds__(256)
void ln_k(const float* __restrict__ x, const float* __restrict__ pos,
          const float* __restrict__ g, const float* __restrict__ b, u16* __restrict__ out)
{
  const int warp = threadIdx.x >> 6, l = threadIdx.x & 63;
  const int row = blockIdx.x * 4 + warp;
  const float4 xv = reinterpret_cast<const float4*>(x + (size_t)row * 256)[l];
  float s = xv.x + xv.y + xv.z + xv.w;
#pragma unroll
  for (int o = 32; o; o >>= 1) s += __shfl_xor(s, o);
  const float mean = s * (1.f / 256.f);
  const float d0 = xv.x - mean, d1 = xv.y - mean, d2 = xv.z - mean, d3 = xv.w - mean;
  float vs = d0 * d0 + d1 * d1 + d2 * d2 + d3 * d3;
#pragma unroll
  for (int o = 32; o; o >>= 1) vs += __shfl_xor(vs, o);
  const float rs = rsqrtf(vs * (1.f / 256.f) + 1e-5f);
  const float4 gv = reinterpret_cast<const float4*>(g)[l];
  const float4 bv = reinterpret_cast<const float4*>(b)[l];
  float o0 = d0 * rs * gv.x + bv.x;
  float o1 = d1 * rs * gv.y + bv.y;
  float o2 = d2 * rs * gv.z + bv.z;
  float o3 = d3 * rs * gv.w + bv.w;
  if (ADDPOS) {
    const float4 pv = reinterpret_cast<const float4*>(pos + (size_t)row * 256)[l];
    o0 += pv.x; o1 += pv.y; o2 += pv.z; o3 += pv.w;
  }
  u16x4 ov; ov.x = f2bf(o0); ov.y = f2bf(o1); ov.z = f2bf(o2); ov.w = f2bf(o3);
  reinterpret_cast<u16x4*>(out + (size_t)row * 256)[l] = ov;
}

// ---------------- fused softmax + loc + multiscale deformable sampling ----------------
__global__ __launch_bounds__(256)
void msdeform_k(const u16* __restrict__ value, const float* __restrict__ oa,
                const float* __restrict__ refpt, float* __restrict__ locout,
                u16* __restrict__ outp)
{
  const int t = threadIdx.x;
  const int rloc = t >> 7;              // row within block
  const int rem = t & 127;
  const int h = rem >> 4, p = rem & 15; // p = lane-in-group = point idx = dim-pair idx
  const int row = blockIdx.x * 2 + rloc;
  const int b = row >> 11;              // Q=2048
  const int lv = p >> 2;
  const float* orow = oa + (size_t)row * 384;

  // ---- softmax over the 16 points of (row,h)
  const float araw = orow[256 + h * 16 + p];
  float mx = araw;
#pragma unroll
  for (int o = 1; o < 16; o <<= 1) mx = fmaxf(mx, __shfl_xor(mx, o, 16));
  const float e = __expf(araw - mx);
  float se = e;
#pragma unroll
  for (int o = 1; o < 16; o <<= 1) se += __shfl_xor(se, o, 16);
  const float aw = e / se;

  // ---- loc = ref + off/normalizer  (write output 1)
  const float2 off = *reinterpret_cast<const float2*>(orow + h * 32 + p * 2);
  const float rn = (lv == 0) ? (1.f / 100.f) : (lv == 1) ? (1.f / 50.f)
                 : (lv == 2) ? (1.f / 25.f) : (1.f / 13.f);
  const float rx = refpt[(size_t)row * 8 + lv * 2 + 0];
  const float ry = refpt[(size_t)row * 8 + lv * 2 + 1];
  const float lx = rx + off.x * rn;
  const float ly = ry + off.y * rn;
  float2 lw; lw.x = lx; lw.y = ly;
  *reinterpret_cast<float2*>(locout + (((size_t)row * 8 + h) * 16 + p) * 2) = lw;

  // ---- this lane's point params
  const int Wl = (lv == 0) ? 100 : (lv == 1) ? 50 : (lv == 2) ? 25 : 13;
  const int st = (lv == 0) ? 0 : (lv == 1) ? 10000 : (lv == 2) ? 12500 : 13125;
  const float Wf = (float)Wl;
  const float xx = lx * Wf - 0.5f, yy = ly * Wf - 0.5f;
  const float xf = floorf(xx), yf = floorf(yy);
  const float wx = xx - xf, wy = yy - yf;
  const int x0 = (int)xf, y0 = (int)yf;
  const int xc0 = min(max(x0, 0), Wl - 1), xc1 = min(max(x0 + 1, 0), Wl - 1);
  const int yc0 = min(max(y0, 0), Wl - 1), yc1 = min(max(y0 + 1, 0), Wl - 1);
  const float vx0 = (x0 >= 0 && x0 < Wl) ? 1.f : 0.f;
  const float vx1 = (x0 + 1 >= 0 && x0 + 1 < Wl) ? 1.f : 0.f;
  const float vy0 = (y0 >= 0 && y0 < Wl) ? 1.f : 0.f;
  const float vy1 = (y0 + 1 >= 0 && y0 + 1 < Wl) ? 1.f : 0.f;
  const int o00 = st + yc0 * Wl + xc0, o01 = st + yc0 * Wl + xc1;
  const int o10 = st + yc1 * Wl + xc0, o11 = st + yc1 * Wl + xc1;
  const float w00 = aw * (1.f - wx) * (1.f - wy) * vx0 * vy0;
  const float w01 = aw * wx * (1.f - wy) * vx1 * vy0;
  const float w10 = aw * (1.f - wx) * wy * vx0 * vy1;
  const float w11 = aw * wx * wy * vx1 * vy1;

  const char* vbase = (const char*)value + (size_t)b * LEN_IN_ * 512 + (size_t)(h * 32 + p * 2) * 2;
  float a0 = 0.f, a1 = 0.f;
#pragma unroll
  for (int q = 0; q < 16; ++q) {
    const int   c00 = __shfl(o00, q, 16), c01 = __shfl(o01, q, 16);
    const int   c10 = __shfl(o10, q, 16), c11 = __shfl(o11, q, 16);
    const float u00 = __shfl(w00, q, 16), u01 = __shfl(w01, q, 16);
    const float u10 = __shfl(w10, q, 16), u11 = __shfl(w11, q, 16);
    const u32 g00 = *reinterpret_cast<const u32*>(vbase + (size_t)c00 * 512);
    const u32 g01 = *reinterpret_cast<const u32*>(vbase + (size_t)c01 * 512);
    const u32 g10 = *reinterpret_cast<const u32*>(vbase + (size_t)c10 * 512);
    const u32 g11 = *reinterpret_cast<const u32*>(vbase + (size_t)c11 * 512);
    union { u32 u; float f; } lo, hi;
    lo.u = g00 << 16; hi.u = g00 & 0xffff0000u; a0 += u00 * lo.f; a1 += u00 * hi.f;
    lo.u = g01 << 16; hi.u = g01 & 0xffff0000u; a0 += u01 * lo.f; a1 += u01 * hi.f;
    lo.u = g10 << 16; hi.u = g10 & 0xffff0000u; a0 += u10 * lo.f; a1 += u10 * hi.f;
    lo.u = g11 << 16; hi.u = g11 & 0xffff0000u; a0 += u11 * lo.f; a1 += u11 * hi.f;
  }
  const u32 res = ((u32)f2bf(a1) << 16) | (u32)f2bf(a0);
  reinterpret_cast<u32*>(outp)[(size_t)row * 128 + h * 16 + p] = res;
}

// ---------------- launch ----------------
extern "C" void kernel_launch(void* const* d_in, const int* in_sizes, int n_in,
                              void* d_out, int out_size, void* d_ws, size_t ws_size,
                              hipStream_t stream)
{
  (void)in_sizes; (void)n_in; (void)out_size; (void)ws_size;
  const float* input  = (const float*)d_in[0];
  const float* pos    = (const float*)d_in[1];
  const float* refpt  = (const float*)d_in[2];
  const float* source = (const float*)d_in[3];
  const float* ln1_g  = (const float*)d_in[7];
  const float* ln1_b  = (const float*)d_in[8];
  const float* ln2_g  = (const float*)d_in[9];
  const float* ln2_b  = (const float*)d_in[10];
  const float* Wv     = (const float*)d_in[11];
  const float* bv     = (const float*)d_in[12];
  const float* Woff   = (const float*)d_in[13];
  const float* boff   = (const float*)d_in[14];
  const float* Wattn  = (const float*)d_in[15];
  const float* battn  = (const float*)d_in[16];
  const float* Wout   = (const float*)d_in[17];
  const float* bout   = (const float*)d_in[18];
  const float* W1     = (const float*)d_in[19];
  const float* b1     = (const float*)d_in[20];
  const float* W2     = (const float*)d_in[21];
  const float* b2     = (const float*)d_in[22];

  char* ws = (char*)d_ws;
  u16*   WvT    = (u16*)  (ws + 0);           // 131072
  u16*   WcombT = (u16*)  (ws + 131072);      // 196608 ([384][256])
  u16*   WoutT  = (u16*)  (ws + 327680);      // 131072
  u16*   W1T    = (u16*)  (ws + 458752);      // 524288
  u16*   W2T    = (u16*)  (ws + 983040);      // 524288
  float* bcomb  = (float*)(ws + 1507328);     // 1536
  u16*   valueB = (u16*)  (ws + 1508864);     // 54,460,416 (MVPAD x 256 bf16)
  u16*   hB     = (u16*)  (ws + 1508864);     // 33,554,432 — reuses valueB (dead after msdeform)
  u16*   qpB    = (u16*)  (ws + 55969280);    // 8,388,608
  u16*   msout  = (u16*)  (ws + 55969280);    // 8,388,608 — reuses qpB (dead after comb GEMM)
  float* oa     = (float*)(ws + 64357888);    // 25,165,824 (dead after msdeform)
  float* xbuf   = (float*)(ws + 89523712);    // 16,777,216
  u16*   xnB    = (u16*)  (ws + 106300928);   // 8,388,608
  // total: 114,689,536 B

  float* out_x   = (float*)d_out;
  float* out_loc = (float*)d_out + (size_t)MQ * DIM_;

  // all weight transposes + combined bias, one kernel
  hipLaunchKernelGGL(prep_weights, dim3(2946), dim3(256), 0, stream,
                     Wv, Woff, Wattn, Wout, W1, W2, boff, battn,
                     WvT, WcombT, WoutT, W1T, W2T, bcomb);

  // qp = LN1(input)*g+b + pos   (bf16)
  hipLaunchKernelGGL((ln_k<true>), dim3(MQ / 4), dim3(256), 0, stream, input, pos, ln1_g, ln1_b, qpB);

  // value = source @ Wv + bv  (bf16 out; A fp32 converted in-reg)
  hipLaunchKernelGGL((gemm_k<1, true>), dim3(MVPAD / 128, 2), dim3(512), 0, stream,
                     (const void*)source, WvT, bv, (const float*)nullptr, (void*)valueB, 256, 256, MV);

  // [offsets|attn] raw = qp @ Wcomb + bcomb (f32, N=384)
  hipLaunchKernelGGL((gemm_k<0, false>), dim3(MQ / 128, 3), dim3(512), 0, stream,
                     (const void*)qpB, WcombT, bcomb, (const float*)nullptr, (void*)oa, 384, 256, MQ);

  // softmax + loc (writes output 1) + deformable sampling -> msout (bf16)
  hipLaunchKernelGGL(msdeform_k, dim3(MQ / 2), dim3(256), 0, stream,
                     valueB, oa, refpt, out_loc, msout);

  // x = input + msout @ Wout + bout (f32)
  hipLaunchKernelGGL((gemm_k<2, false>), dim3(MQ / 128, 2), dim3(512), 0, stream,
                     (const void*)msout, WoutT, bout, input, (void*)xbuf, 256, 256, MQ);

  // xn = LN2(x) (bf16)
  hipLaunchKernelGGL((ln_k<false>), dim3(MQ / 4), dim3(256), 0, stream, xbuf, (const float*)nullptr, ln2_g, ln2_b, xnB);

  // h = relu(xn @ W1 + b1) (bf16)
  hipLaunchKernelGGL((gemm_k<3, false>), dim3(MQ / 128, DFF / 128), dim3(512), 0, stream,
                     (const void*)xnB, W1T, b1, (const float*)nullptr, (void*)hB, DFF, 256, MQ);

  // out_x = x + h @ W2 + b2 (f32)
  hipLaunchKernelGGL((gemm_k<2, false>), dim3(MQ / 128, 2), dim3(512), 0, stream,
                     (const void*)hB, W2T, b2, xbuf, (void*)out_x, 256, 1024, MQ);
}